// Round 7
// baseline (743.843 us; speedup 1.0000x reference)
//
#include <hip/hip_runtime.h>

// Problem constants (fixed by reference)
#define CC 32
#define HH 256
#define WW 512
#define NN 4
#define MAXD 48

// Round-7: barrier-free per-wave async pipeline.
// Evidence: R5 (global-L loop) 96us, R6 (all-LDS, 3 barriers) 123us, all pipes
// <25% busy, ~1800 cyc/iter effective -> phase-correlated stalls, bursty HBM.
// Fix: waves fully independent (ZERO __syncthreads). Each wave owns 12d x 256w,
// streams c=0..31 with depth-3 async R staging into wave-private LDS via
// global_load_lds + counted vmcnt (m135 FIFO semantics); L via 4-deep reg
// rotation (compiler-tracked). sched_barrier(0) pins step boundaries so the
// hand-counted vmcnt(9/6/3/0) exactly drains group c (rule #18 guard).
// R read 4x/block (per-wave copies) -> same row -> L2 absorbs; HBM unchanged.
// LDS = 4 waves x 4 bufs x 304 floats = 19456 B. VGPR ~100 true, bound (256,4).
#define WT 256
#define RW (WT + MAXD)    // 304 r columns per buffer (w0-48 .. w0+255)
#define DTILE 12          // d per wave; d0 = 12*dg (mult of 4 -> aligned window)
#define WTILE 4           // w per lane; wb = 4*lane -> aligned float4

__global__ __launch_bounds__(256, 4)
void cost_volume_kernel(const float* __restrict__ L,
                        const float* __restrict__ R,
                        float* __restrict__ out)
{
    __shared__ float r_s[4][4][RW];      // [wave][buf][col], wave-private, 19456 B

    const int t    = threadIdx.x;        // 0..255
    const int lane = t & 63;
    const int dg   = t >> 6;             // wave id 0..3 (owns d0 = 12*dg)
    const int w0   = blockIdx.x * WT;    // 0 or 256
    const int h    = blockIdx.y;
    const int n    = blockIdx.z;

    const size_t chw  = (size_t)HH * WW;                       // channel stride
    const size_t rowB = (size_t)n * CC * chw + (size_t)h * WW; // (n, c=0, h, 0)

    const int wb = lane * WTILE;         // 0..252, multiple of 4
    const int d0 = dg * DTILE;           // 0,12,24,36
    // buf col for (w=w0+wb+i, d=d0+k) is wb+i+48-d0-k -> window [wb+37-d0,
    // wb+51-d0]; aligned 16-float superset starts at:
    const int jA = wb + 36 - d0;         // multiple of 4; 0..288, +15 <= 303

    float acc[DTILE][WTILE];
    #pragma unroll
    for (int k = 0; k < DTILE; ++k)
        #pragma unroll
        for (int i = 0; i < WTILE; ++i)
            acc[k][i] = 0.f;

    // Zero the w<0 pad (buf floats 0..47) once; masked DMA never writes there.
    if (w0 == 0 && lane < 12) {
        #pragma unroll
        for (int b = 0; b < 4; ++b)
            *(float4*)&r_s[dg][b][4 * lane] = make_float4(0.f, 0.f, 0.f, 0.f);
    }

    const int   fullR = (w0 != 0);
    const float* Rbase = R + rowB + w0 - MAXD;    // col 0 of each buf
    const float* lp    = L + rowB + w0 + wb;      // this lane's L float4

    // Per step per wave: exactly 3 vmem instrs {L-reg, R1, R2} -> counted vmcnt.
#define ISSUE(s) do {                                                         \
        const float* rb = Rbase + (size_t)(s) * chw;                          \
        float* lb = &r_s[dg][(s) & 3][0];                                     \
        if (fullR | (lane >= 12))                                             \
            __builtin_amdgcn_global_load_lds(                                 \
                (const __attribute__((address_space(1))) void*)(rb + 4*lane), \
                (__attribute__((address_space(3))) void*)lb, 16, 0, 0);       \
        if (lane < 12)                                                        \
            __builtin_amdgcn_global_load_lds(                                 \
                (const __attribute__((address_space(1))) void*)(rb + 256 + 4*lane), \
                (__attribute__((address_space(3))) void*)(lb + 256), 16, 0, 0); \
    } while (0)

#define WAITN(nv) asm volatile("s_waitcnt vmcnt(" #nv ")" ::: "memory")
#define SCHED0()  __builtin_amdgcn_sched_barrier(0)

    float4 lv[4];
    lv[0] = *(const float4*)(lp);
    ISSUE(0); SCHED0();
    lv[1] = *(const float4*)(lp + chw);
    ISSUE(1); SCHED0();
    lv[2] = *(const float4*)(lp + 2 * chw);
    ISSUE(2); SCHED0();

#define STEP(c, W) do {                                                       \
        if ((c) + 3 < CC) {                                                   \
            lv[((c) + 3) & 3] = *(const float4*)(lp + (size_t)((c)+3) * chw); \
            ISSUE((c) + 3);                                                   \
        }                                                                     \
        WAITN(W);                                                             \
        {                                                                     \
            float rv[16];                                                     \
            const float* rs = &r_s[dg][(c) & 3][jA];                          \
            *(float4*)&rv[0]  = *(const float4*)(rs);                         \
            *(float4*)&rv[4]  = *(const float4*)(rs + 4);                     \
            *(float4*)&rv[8]  = *(const float4*)(rs + 8);                     \
            *(float4*)&rv[12] = *(const float4*)(rs + 12);                    \
            const float4 lf = lv[(c) & 3];                                    \
            _Pragma("unroll")                                                 \
            for (int k = 0; k < DTILE; ++k) {                                 \
                acc[k][0] += lf.x * rv[12 - k];  /* idx 1..15 compile-time */ \
                acc[k][1] += lf.y * rv[13 - k];                               \
                acc[k][2] += lf.z * rv[14 - k];                               \
                acc[k][3] += lf.w * rv[15 - k];                               \
            }                                                                 \
        }                                                                     \
        SCHED0();                                                             \
    } while (0)

    STEP( 0, 9); STEP( 1, 9); STEP( 2, 9); STEP( 3, 9); STEP( 4, 9);
    STEP( 5, 9); STEP( 6, 9); STEP( 7, 9); STEP( 8, 9); STEP( 9, 9);
    STEP(10, 9); STEP(11, 9); STEP(12, 9); STEP(13, 9); STEP(14, 9);
    STEP(15, 9); STEP(16, 9); STEP(17, 9); STEP(18, 9); STEP(19, 9);
    STEP(20, 9); STEP(21, 9); STEP(22, 9); STEP(23, 9); STEP(24, 9);
    STEP(25, 9); STEP(26, 9); STEP(27, 9); STEP(28, 9);
    STEP(29, 6); STEP(30, 3); STEP(31, 0);

#undef STEP
#undef ISSUE
#undef WAITN
#undef SCHED0

    const float inv = 1.0f / 32.0f;      // mean over C, exact pow2
    #pragma unroll
    for (int k = 0; k < DTILE; ++k) {
        const int d = d0 + k;
        float4 o = make_float4(acc[k][0] * inv, acc[k][1] * inv,
                               acc[k][2] * inv, acc[k][3] * inv);
        *(float4*)(out + (((size_t)n * MAXD + d) * HH + h) * WW + w0 + wb) = o;
    }
}

extern "C" void kernel_launch(void* const* d_in, const int* in_sizes, int n_in,
                              void* d_out, int out_size, void* d_ws, size_t ws_size,
                              hipStream_t stream) {
    const float* L = (const float*)d_in[0];
    const float* R = (const float*)d_in[1];
    float* out = (float*)d_out;
    // d_in[2] (use_naive) is ignored per reference.
    dim3 grid(WW / WT, HH, NN);          // 2 x 256 x 4 = 2048 blocks
    cost_volume_kernel<<<grid, dim3(256, 1, 1), 0, stream>>>(L, R, out);
}

// Round 8
// 241.478 us; speedup vs baseline: 3.0804x; 3.0804x over previous
//
#include <hip/hip_runtime.h>

// Problem constants (fixed by reference)
#define CC 32
#define HH 256
#define WW 512
#define NN 4
#define MAXD 48

// Round-8: block-granularity experiment. Seven rounds of evidence: every
// clean variant (R0 4-wave/128VGPR, R5 6-wave/80VGPR, any occupancy) = 96 us
// +-0.1%; all pipes <25% busy; ~3600 cyc/iter effective vs ~200 cyc chain.
// The only never-varied parameter: 2048 short-lived one-row blocks. Theory:
// per-BLOCK cost (dispatch/teardown/cold-start) dominates, invariant to block
// internals. Test: identical R5 compute core, but each block processes 4
// consecutive h rows (grid 512 = 2 blocks/CU exactly, zero tail, 4x fewer
// launches). Per row: barrier; restage R; barrier; compute (proven pattern).
// Discriminator: dur -> ~40-55 us if theory right; pinned ~96 if wrong.
#define WT 256
#define RW (WT + MAXD)    // 304 r columns staged (w0-48 .. w0+255)
#define DTILE 8           // d per thread; d0 = 8*dg (mult of 4 -> aligned window)
#define WTILE 4           // w per thread; wb mult of 4 -> aligned float4
#define NT 384            // 6 waves/block; 64 w-groups x 6 d-groups
#define HT 4              // h rows per block

__global__ __launch_bounds__(NT, 6)
void cost_volume_kernel(const float* __restrict__ L,
                        const float* __restrict__ R,
                        float* __restrict__ out)
{
    __shared__ float r_s[CC][RW];        // 38 KB, r only; l stays in global/regs

    const int t   = threadIdx.x;         // 0..383
    const int w0  = blockIdx.x * WT;     // 0 or 256
    const int hb  = blockIdx.y * HT;     // base h of this block's 4 rows
    const int n   = blockIdx.z;

    const size_t chw = (size_t)HH * WW;  // channel stride

    const int wg = t & 63;               // lane; dg wave-uniform
    const int dg = t >> 6;               // 0..5
    const int wb = wg * WTILE;           // 0..252, multiple of 4
    const int d0 = dg * DTILE;           // 0,8,16,24,32,40
    // r_s col for (local w=wb+i, d=d0+k) is wb+i+48-d0-k, i in [0,3], k in [0,7]
    // -> window [wb+41-d0, wb+51-d0]; aligned 12-float superset starts at:
    const int jA = wb + 40 - d0;         // multiple of 4; 0..292, +11 <= 303

    #pragma unroll 1
    for (int hh = 0; hh < HT; ++hh) {
        const int h = hb + hh;
        const size_t rowB = (size_t)n * CC * chw + (size_t)h * WW; // (n,0,h,0)

        if (hh) __syncthreads();         // prev row's compute done before restage

        // ---- stage r row: 32 x 76 float4 = 2432 slots, ~6.3/thread, coalesced
        #pragma unroll
        for (int k = 0; k < 7; ++k) {
            int idx = t + NT * k;        // 0..2687
            if (idx < 2432) {
                int c   = idx / 76;      // 76 float4 per row
                int j4  = idx - c * 76;
                int g   = w0 - MAXD + 4 * j4;    // global w of this float4
                float4 v = make_float4(0.f, 0.f, 0.f, 0.f);
                if (g >= 0)              // w<0 -> zeros (zero pad / w<d)
                    v = *(const float4*)(R + rowB + (size_t)c * chw + g);
                *(float4*)&r_s[c][4 * j4] = v;
            }
        }
        __syncthreads();

        float acc[DTILE][WTILE];
        #pragma unroll
        for (int k = 0; k < DTILE; ++k)
            #pragma unroll
            for (int i = 0; i < WTILE; ++i)
                acc[k][i] = 0.f;

        const float* lp = L + rowB + w0 + wb;     // + c*chw per channel, aligned
        float4 lv0 = *(const float4*)(lp);        // 2-deep prefetch
        float4 lv1 = *(const float4*)(lp + chw);
        for (int c = 0; c < CC; ++c) {
            float4 lnext;
            if (c + 2 < CC)                       // uniform branch
                lnext = *(const float4*)(lp + (size_t)(c + 2) * chw);
            float rv[12];
            #pragma unroll
            for (int q = 0; q < 3; ++q)
                *(float4*)&rv[4 * q] = *(const float4*)&r_s[c][jA + 4 * q];
            #pragma unroll
            for (int k = 0; k < DTILE; ++k) {
                acc[k][0] += lv0.x * rv[8 - k];   // offsets 1..11, compile-time
                acc[k][1] += lv0.y * rv[9 - k];
                acc[k][2] += lv0.z * rv[10 - k];
                acc[k][3] += lv0.w * rv[11 - k];
            }
            lv0 = lv1;
            lv1 = lnext;
        }

        const float inv = 1.0f / 32.0f;  // mean over C, exact pow2
        #pragma unroll
        for (int k = 0; k < DTILE; ++k) {
            const int d = d0 + k;
            float4 o = make_float4(acc[k][0] * inv, acc[k][1] * inv,
                                   acc[k][2] * inv, acc[k][3] * inv);
            *(float4*)(out + (((size_t)n * MAXD + d) * HH + h) * WW + w0 + wb) = o;
        }
    }
}

extern "C" void kernel_launch(void* const* d_in, const int* in_sizes, int n_in,
                              void* d_out, int out_size, void* d_ws, size_t ws_size,
                              hipStream_t stream) {
    const float* L = (const float*)d_in[0];
    const float* R = (const float*)d_in[1];
    float* out = (float*)d_out;
    // d_in[2] (use_naive) is ignored per reference.
    dim3 grid(WW / WT, HH / HT, NN);     // 2 x 64 x 4 = 512 blocks, 2/CU exact
    cost_volume_kernel<<<grid, dim3(NT, 1, 1), 0, stream>>>(L, R, out);
}